// Round 7
// baseline (942.837 us; speedup 1.0000x reference)
//
#include <hip/hip_runtime.h>

namespace {

constexpr int NTH = 512;   // threads per block
constexpr int NB  = 512;   // GRU batch (original T)
constexpr int HID = 128;
constexpr int G3  = 384;
constexpr int SS  = 128;   // scan steps (original B)
constexpr int CH  = 20;    // padded LDS chunk stride for fallback kernel

typedef float    f32x2 __attribute__((ext_vector_type(2)));
typedef float    f32x4 __attribute__((ext_vector_type(4)));
typedef _Float16 f16;
typedef f16      f16x8 __attribute__((ext_vector_type(8)));

__device__ __forceinline__ f32x2 pk_fma(f32x2 a, f32x2 b, f32x2 c) {
#if __has_builtin(__builtin_elementwise_fma)
    return __builtin_elementwise_fma(a, b, c);
#else
    f32x2 r; r.x = fmaf(a.x, b.x, c.x); r.y = fmaf(a.y, b.y, c.y); return r;
#endif
}

template <int CTRL>
__device__ __forceinline__ float add_dpp(float v) {
    int moved = __builtin_amdgcn_update_dpp(0, __float_as_int(v), CTRL, 0xf, 0xf, true);
    return v + __int_as_float(moved);
}
__device__ __forceinline__ float wave_red8(float v) {
    v = add_dpp<0x111>(v);
    v = add_dpp<0x112>(v);
    v = add_dpp<0x114>(v);
    return v;
}

__device__ __forceinline__ float dot4acc(float4 a, float4 b, float acc) {
    acc = fmaf(a.x, b.x, acc);
    acc = fmaf(a.y, b.y, acc);
    acc = fmaf(a.z, b.z, acc);
    acc = fmaf(a.w, b.w, acc);
    return acc;
}

__device__ __forceinline__ float fsig(float x)  { return 1.f / (1.f + __expf(-x)); }
__device__ __forceinline__ float ftanh_(float x){ const float e = __expf(2.f * x); return 1.f - 2.f / (e + 1.f); }

__device__ __forceinline__ f16x8 zero8() {
    f16x8 z;
    #pragma unroll
    for (int e = 0; e < 8; ++e) z[e] = (f16)0.f;
    return z;
}

// ============================================================================
// Kernel 1: px GEMM, TRANSPOSED output.
// pxt[j][m] = sum_k W[j][k]*X[m][k] + bih[j] + (j<256 ? bhh[j] : 0)
// j in [0,384), m = s*512+n in [0,65536). Output row-major [384][65536] so the
// recurrence reads one float4 (4 consecutive n) per gate.
// grid (m-tiles=512, g-tiles=3), 256 thr, tile 128x128, 8x8 per thread.
// ============================================================================
constexpr int BKG = 32;
constexpr int TSTR = 132;

__global__ __launch_bounds__(256, 4) void px_gemm_t(
    const float* __restrict__ X,    // [65536][kin]
    const float* __restrict__ Wm,   // [384][kin]   (w_ih)
    const float* __restrict__ bih,
    const float* __restrict__ bhh,
    float* __restrict__ pxt,        // [384][65536]
    int kin)
{
    __shared__ __align__(16) float Gt[BKG * TSTR];  // Gt[k][g_local]
    __shared__ __align__(16) float Xt[BKG * TSTR];  // Xt[k][m_local]

    const int tid = threadIdx.x;
    const int m0  = blockIdx.x * 128;
    const int g0  = blockIdx.y * 128;
    const int tr  = tid >> 4;   // g-tile 0..15
    const int tc  = tid & 15;   // m-tile 0..15

    f32x2 acc2[8][4];           // [g-row i][m-pair j]
    #pragma unroll
    for (int i = 0; i < 8; ++i)
        #pragma unroll
        for (int j = 0; j < 4; ++j) acc2[i][j] = f32x2{0.f, 0.f};

    const int srow = tid >> 3;
    const int sf4  = (tid & 7) * 4;

    for (int kt = 0; kt < kin; kt += BKG) {
        #pragma unroll
        for (int p = 0; p < 4; ++p) {
            const int r = p * 32 + srow;
            const float4 vg = *reinterpret_cast<const float4*>(Wm + (size_t)(g0 + r) * kin + kt + sf4);
            Gt[(sf4 + 0) * TSTR + r] = vg.x;
            Gt[(sf4 + 1) * TSTR + r] = vg.y;
            Gt[(sf4 + 2) * TSTR + r] = vg.z;
            Gt[(sf4 + 3) * TSTR + r] = vg.w;
            const float4 vx = *reinterpret_cast<const float4*>(X + (size_t)(m0 + r) * kin + kt + sf4);
            Xt[(sf4 + 0) * TSTR + r] = vx.x;
            Xt[(sf4 + 1) * TSTR + r] = vx.y;
            Xt[(sf4 + 2) * TSTR + r] = vx.z;
            Xt[(sf4 + 3) * TSTR + r] = vx.w;
        }
        __syncthreads();

        #pragma unroll 8
        for (int kk = 0; kk < BKG; ++kk) {
            const float4 g0v = *reinterpret_cast<const float4*>(&Gt[kk * TSTR + tr * 8]);
            const float4 g1v = *reinterpret_cast<const float4*>(&Gt[kk * TSTR + tr * 8 + 4]);
            const float4 x0 = *reinterpret_cast<const float4*>(&Xt[kk * TSTR + tc * 8]);
            const float4 x1 = *reinterpret_cast<const float4*>(&Xt[kk * TSTR + tc * 8 + 4]);
            const f32x2 wp[4] = { f32x2{x0.x, x0.y}, f32x2{x0.z, x0.w},
                                  f32x2{x1.x, x1.y}, f32x2{x1.z, x1.w} };
            const float ar[8] = { g0v.x, g0v.y, g0v.z, g0v.w, g1v.x, g1v.y, g1v.z, g1v.w };
            #pragma unroll
            for (int i = 0; i < 8; ++i) {
                const f32x2 av = f32x2{ar[i], ar[i]};
                #pragma unroll
                for (int j = 0; j < 4; ++j)
                    acc2[i][j] = pk_fma(av, wp[j], acc2[i][j]);
            }
        }
        __syncthreads();
    }

    // epilogue: per-g-row bias (broadcast along m), coalesced stores along m
    const int gbase = g0 + tr * 8;
    float4 b0 = *reinterpret_cast<const float4*>(bih + gbase);
    float4 b1 = *reinterpret_cast<const float4*>(bih + gbase + 4);
    if (g0 < 256) {  // r,z blocks fold b_hh too
        const float4 h0 = *reinterpret_cast<const float4*>(bhh + gbase);
        const float4 h1 = *reinterpret_cast<const float4*>(bhh + gbase + 4);
        b0.x += h0.x; b0.y += h0.y; b0.z += h0.z; b0.w += h0.w;
        b1.x += h1.x; b1.y += h1.y; b1.z += h1.z; b1.w += h1.w;
    }
    const float bias[8] = { b0.x, b0.y, b0.z, b0.w, b1.x, b1.y, b1.z, b1.w };
    #pragma unroll
    for (int i = 0; i < 8; ++i) {
        const size_t rowoff = (size_t)(gbase + i) * (size_t)(SS * NB) + m0 + tc * 8;
        float4 o0, o1;
        o0.x = acc2[i][0].x + bias[i]; o0.y = acc2[i][0].y + bias[i];
        o0.z = acc2[i][1].x + bias[i]; o0.w = acc2[i][1].y + bias[i];
        o1.x = acc2[i][2].x + bias[i]; o1.y = acc2[i][2].y + bias[i];
        o1.z = acc2[i][3].x + bias[i]; o1.w = acc2[i][3].y + bias[i];
        *reinterpret_cast<float4*>(pxt + rowoff)     = o0;
        *reinterpret_cast<float4*>(pxt + rowoff + 4) = o1;
    }
}

// ============================================================================
// Kernel 2: MFMA recurrence v3. 32 blocks x 512 threads; 16 rows/block.
// W in SINGLE f16 (48 VGPR resident); h split hi/lo (2 MFMA passes, 24 MFMA).
// px read as 3 float4/step from transposed pxt, issued at step-top.
// #pragma unroll 1 on the step loop (R6 suspect: unroll-x2 pressure spike).
// ============================================================================
__global__ __launch_bounds__(NTH, 1) void gru_rec_v3(
    const float* __restrict__ pxt,  // [384][65536]  (biases folded)
    const float* __restrict__ whh,  // [384][128]
    const float* __restrict__ bhh,  // [384]
    float* __restrict__ yd)         // [SS][NB][HID]
{
    __shared__ _Float16 hlds[2][2][16 * HID];   // [dbuf][hi|lo][m*128+k], XOR-swizzled

    const int tid  = threadIdx.x;
    const int lane = tid & 63;
    const int w    = tid >> 6;      // wave 0..7 = gate-column tile
    const int l15  = lane & 15;
    const int q    = lane >> 4;     // lane quadrant 0..3
    const int colc = w * 16 + l15;  // hidden column owned (0..127)
    const int row0 = blockIdx.x * 16;

    // ---- W fragments, single f16 (B-frag: lane l holds W[kt*32+q*8+e][l15]) ----
    f16x8 Wf[3][4];
    #pragma unroll
    for (int g = 0; g < 3; ++g) {
        #pragma unroll
        for (int kt = 0; kt < 4; ++kt) {
            const float* src = whh + (size_t)(g * HID + colc) * HID + kt * 32 + q * 8;
            const float4 a = *reinterpret_cast<const float4*>(src);
            const float4 b = *reinterpret_cast<const float4*>(src + 4);
            f16x8 f;
            f[0] = (f16)a.x; f[1] = (f16)a.y; f[2] = (f16)a.z; f[3] = (f16)a.w;
            f[4] = (f16)b.x; f[5] = (f16)b.y; f[6] = (f16)b.z; f[7] = (f16)b.w;
            Wf[g][kt] = f;
        }
    }
    const float bhn = bhh[256 + colc];

    float hstate[4] = {0.f, 0.f, 0.f, 0.f};
    f16x8 Ahi[4], Alo[4];
    #pragma unroll
    for (int kt = 0; kt < 4; ++kt) { Ahi[kt] = zero8(); Alo[kt] = zero8(); }

    const size_t M = (size_t)SS * NB;   // 65536
    const int mrow = row0 + q * 4;
    const float* p0 = pxt + (size_t)(colc)       * M + mrow;
    const float* p1 = pxt + (size_t)(128 + colc) * M + mrow;
    const float* p2 = pxt + (size_t)(256 + colc) * M + mrow;
    float* ybase = yd + (size_t)mrow * HID + colc;

    #pragma unroll 1
    for (int s = 0; s < SS; ++s) {
        // px for THIS step, issued before MFMA, consumed after (latency hidden)
        const size_t so = (size_t)s * NB;
        const f32x4 pcr = *reinterpret_cast<const f32x4*>(p0 + so);
        const f32x4 pcz = *reinterpret_cast<const f32x4*>(p1 + so);
        const f32x4 pcn = *reinterpret_cast<const f32x4*>(p2 + so);

        // ---- gh = h @ w_hh.T : 24 MFMA, 6 independent chains of depth 4 ----
        f32x4 a0R = {0.f,0.f,0.f,0.f}, a1R = {0.f,0.f,0.f,0.f};
        f32x4 a0Z = {0.f,0.f,0.f,0.f}, a1Z = {0.f,0.f,0.f,0.f};
        f32x4 a0N = {0.f,0.f,0.f,0.f}, a1N = {0.f,0.f,0.f,0.f};
        #pragma unroll
        for (int kt = 0; kt < 2; ++kt) {
            a0R = __builtin_amdgcn_mfma_f32_16x16x32_f16(Ahi[kt],     Wf[0][kt],     a0R, 0, 0, 0);
            a0Z = __builtin_amdgcn_mfma_f32_16x16x32_f16(Ahi[kt],     Wf[1][kt],     a0Z, 0, 0, 0);
            a0N = __builtin_amdgcn_mfma_f32_16x16x32_f16(Ahi[kt],     Wf[2][kt],     a0N, 0, 0, 0);
            a1R = __builtin_amdgcn_mfma_f32_16x16x32_f16(Ahi[kt + 2], Wf[0][kt + 2], a1R, 0, 0, 0);
            a1Z = __builtin_amdgcn_mfma_f32_16x16x32_f16(Ahi[kt + 2], Wf[1][kt + 2], a1Z, 0, 0, 0);
            a1N = __builtin_amdgcn_mfma_f32_16x16x32_f16(Ahi[kt + 2], Wf[2][kt + 2], a1N, 0, 0, 0);
        }
        #pragma unroll
        for (int kt = 0; kt < 2; ++kt) {
            a0R = __builtin_amdgcn_mfma_f32_16x16x32_f16(Alo[kt],     Wf[0][kt],     a0R, 0, 0, 0);
            a0Z = __builtin_amdgcn_mfma_f32_16x16x32_f16(Alo[kt],     Wf[1][kt],     a0Z, 0, 0, 0);
            a0N = __builtin_amdgcn_mfma_f32_16x16x32_f16(Alo[kt],     Wf[2][kt],     a0N, 0, 0, 0);
            a1R = __builtin_amdgcn_mfma_f32_16x16x32_f16(Alo[kt + 2], Wf[0][kt + 2], a1R, 0, 0, 0);
            a1Z = __builtin_amdgcn_mfma_f32_16x16x32_f16(Alo[kt + 2], Wf[1][kt + 2], a1Z, 0, 0, 0);
            a1N = __builtin_amdgcn_mfma_f32_16x16x32_f16(Alo[kt + 2], Wf[2][kt + 2], a1N, 0, 0, 0);
        }
        const f32x4 accR = a0R + a1R;
        const f32x4 accZ = a0Z + a1Z;
        const f32x4 accN = a0N + a1N;

        // ---- gates (C row m=q*4+r, col=colc), y store, h->LDS f16 hi/lo ----
        _Float16* wb0 = &hlds[(s + 1) & 1][0][0];
        _Float16* wb1 = &hlds[(s + 1) & 1][1][0];
        #pragma unroll
        for (int r = 0; r < 4; ++r) {
            const float rr = fsig(pcr[r] + accR[r]);
            const float zz = fsig(pcz[r] + accZ[r]);
            const float nn = ftanh_(pcn[r] + rr * (accN[r] + bhn));
            const float hn = (1.f - zz) * nn + zz * hstate[r];
            hstate[r] = hn;
            ybase[(so + (size_t)r) * HID] = hn;
            const int m   = q * 4 + r;
            const int idx = (m * HID + colc) ^ ((m & 7) << 3);
            const f16 hh = (f16)hn;
            wb0[idx] = hh;
            wb1[idx] = (f16)(hn - (float)hh);
        }

        __syncthreads();

        // ---- A-frags for h[s+1]: lane l reads h[l15][kt*32+q*8 .. +7] ----
        const _Float16* rb0 = &hlds[(s + 1) & 1][0][0];
        const _Float16* rb1 = &hlds[(s + 1) & 1][1][0];
        #pragma unroll
        for (int kt = 0; kt < 4; ++kt) {
            const int idx = (l15 * HID + kt * 32 + q * 8) ^ ((l15 & 7) << 3);
            Ahi[kt] = *reinterpret_cast<const f16x8*>(rb0 + idx);
            Alo[kt] = *reinterpret_cast<const f16x8*>(rb1 + idx);
        }
    }
}

// ============================================================================
// Fallback: R1 fused kernel (used only if workspace is too small for pxt).
// ============================================================================
__global__ __launch_bounds__(NTH) void gru3_fused(
    const float* __restrict__ xin,
    const float* __restrict__ wih0, const float* __restrict__ whh0,
    const float* __restrict__ bih0, const float* __restrict__ bhh0,
    const float* __restrict__ wih1, const float* __restrict__ whh1,
    const float* __restrict__ bih1, const float* __restrict__ bhh1,
    const float* __restrict__ wih2, const float* __restrict__ whh2,
    const float* __restrict__ bih2, const float* __restrict__ bhh2,
    float* __restrict__ out)
{
    __shared__ __align__(16) float xb[2][2 * 8 * CH];
    __shared__ __align__(16) float hb[2 * 8 * CH];
    __shared__ float pxl[2][G3];
    __shared__ float ghl[2][G3];
    __shared__ float bsum[2 * HID];
    __shared__ float bin_[HID];
    __shared__ float bhn_[HID];

    const int tid  = threadIdx.x;
    const int kgrp = tid & 7;
    const int gt   = tid >> 3;
    const int g0   = gt * 6;
    const int row0 = blockIdx.x * 2;

    float4 wih[6][4];
    float4 whh[6][4];

    for (int layer = 0; layer < 3; ++layer) {
        const float *wi, *wh, *bi, *bh, *xs;
        float* yd;
        int kin;
        if (layer == 0)      { wi = wih0; wh = whh0; bi = bih0; bh = bhh0; xs = xin; yd = out; kin = 64;  }
        else if (layer == 1) { wi = wih1; wh = whh1; bi = bih1; bh = bhh1; xs = out; yd = out; kin = HID; }
        else                 { wi = wih2; wh = whh2; bi = bih2; bh = bhh2; xs = out; yd = out; kin = HID; }

        #pragma unroll
        for (int gg = 0; gg < 6; ++gg) {
            const int g = g0 + gg;
            #pragma unroll
            for (int q = 0; q < 4; ++q) {
                const int k = kgrp * 16 + q * 4;
                whh[gg][q] = *reinterpret_cast<const float4*>(wh + g * HID + k);
                if (k < kin)
                    wih[gg][q] = *reinterpret_cast<const float4*>(wi + g * kin + k);
                else
                    wih[gg][q] = make_float4(0.f, 0.f, 0.f, 0.f);
            }
        }

        for (int i = tid; i < 2 * HID; i += NTH) bsum[i] = bi[i] + bh[i];
        for (int i = tid; i < HID; i += NTH) { bin_[i] = bi[256 + i]; bhn_[i] = bh[256 + i]; }
        for (int i = tid; i < 2 * 8 * CH; i += NTH) { hb[i] = 0.f; xb[0][i] = 0.f; xb[1][i] = 0.f; }
        __syncthreads();
        if (tid < 256) {
            const int n = tid >> 7, j = tid & 127;
            if (j < kin)
                xb[0][n * (8 * CH) + (j >> 4) * CH + (j & 15)] = xs[(0 * NB + row0 + n) * kin + j];
        }
        __syncthreads();

        float ypend = 0.f;
        bool  have_y = false;

        for (int s = 0; s < SS; ++s) {
            float xpref = 0.f;
            if (tid >= 256) {
                const int t2 = tid - 256;
                const int n = t2 >> 7, j = t2 & 127;
                if (s + 1 < SS && j < kin)
                    xpref = xs[((s + 1) * NB + row0 + n) * kin + j];
            } else if (have_y) {
                const int n = tid >> 7, j = tid & 127;
                yd[((s - 1) * NB + row0 + n) * HID + j] = ypend;
            }

            float accp[2][6], accg[2][6];
            #pragma unroll
            for (int n = 0; n < 2; ++n)
                #pragma unroll
                for (int gg = 0; gg < 6; ++gg) { accp[n][gg] = 0.f; accg[n][gg] = 0.f; }

            const float* xcur = xb[s & 1];
            #pragma unroll
            for (int q = 0; q < 4; ++q) {
                const int off = kgrp * CH + q * 4;
                const float4 x0 = *reinterpret_cast<const float4*>(xcur + off);
                const float4 x1 = *reinterpret_cast<const float4*>(xcur + 8 * CH + off);
                const float4 h0 = *reinterpret_cast<const float4*>(hb + off);
                const float4 h1 = *reinterpret_cast<const float4*>(hb + 8 * CH + off);
                #pragma unroll
                for (int gg = 0; gg < 6; ++gg) {
                    accp[0][gg] = dot4acc(x0, wih[gg][q], accp[0][gg]);
                    accp[1][gg] = dot4acc(x1, wih[gg][q], accp[1][gg]);
                    accg[0][gg] = dot4acc(h0, whh[gg][q], accg[0][gg]);
                    accg[1][gg] = dot4acc(h1, whh[gg][q], accg[1][gg]);
                }
            }

            #pragma unroll
            for (int n = 0; n < 2; ++n)
                #pragma unroll
                for (int gg = 0; gg < 6; ++gg) {
                    const float rp = wave_red8(accp[n][gg]);
                    const float rg = wave_red8(accg[n][gg]);
                    if (kgrp == 7) { pxl[n][g0 + gg] = rp; ghl[n][g0 + gg] = rg; }
                }
            __syncthreads();

            if (tid < 256) {
                const int n = tid >> 7, j = tid & 127;
                const float pr = pxl[n][j]       + ghl[n][j]       + bsum[j];
                const float pz = pxl[n][j + 128] + ghl[n][j + 128] + bsum[j + 128];
                const float gn = ghl[n][j + 256] + bhn_[j];
                const float pn = pxl[n][j + 256] + bin_[j];
                const float r  = fsig(pr);
                const float z  = fsig(pz);
                const float nn = ftanh_(pn + r * gn);
                const int hoff = n * (8 * CH) + (j >> 4) * CH + (j & 15);
                const float hold = hb[hoff];
                const float hnew = (1.f - z) * nn + z * hold;
                hb[hoff] = hnew;
                ypend = hnew;
                have_y = true;
            } else {
                const int t2 = tid - 256;
                const int n = t2 >> 7, j = t2 & 127;
                if (s + 1 < SS && j < kin)
                    xb[(s + 1) & 1][n * (8 * CH) + (j >> 4) * CH + (j & 15)] = xpref;
            }
            __syncthreads();
        }

        if (tid < 256) {
            const int n = tid >> 7, j = tid & 127;
            yd[((SS - 1) * NB + row0 + n) * HID + j] = ypend;
        }
        __syncthreads();
    }
}

}  // namespace

extern "C" void kernel_launch(void* const* d_in, const int* in_sizes, int n_in,
                              void* d_out, int out_size, void* d_ws, size_t ws_size,
                              hipStream_t stream)
{
    (void)in_sizes; (void)n_in; (void)out_size;
    const float* xin = (const float*)d_in[0];
    const float* wih[3] = { (const float*)d_in[1], (const float*)d_in[5], (const float*)d_in[9]  };
    const float* whh[3] = { (const float*)d_in[2], (const float*)d_in[6], (const float*)d_in[10] };
    const float* bih[3] = { (const float*)d_in[3], (const float*)d_in[7], (const float*)d_in[11] };
    const float* bhh[3] = { (const float*)d_in[4], (const float*)d_in[8], (const float*)d_in[12] };
    float* out = (float*)d_out;

    const size_t need = (size_t)G3 * SS * NB * sizeof(float);  // 96 MB pxt buffer
    if (ws_size >= need) {
        float* pxt = (float*)d_ws;
        for (int l = 0; l < 3; ++l) {
            const float* A = (l == 0) ? xin : out;
            const int kin = (l == 0) ? 64 : HID;
            px_gemm_t<<<dim3((SS * NB) / 128, 3), dim3(256), 0, stream>>>(
                A, wih[l], bih[l], bhh[l], pxt, kin);
            gru_rec_v3<<<dim3(NB / 16), dim3(NTH), 0, stream>>>(pxt, whh[l], bhh[l], out);
        }
    } else {
        gru3_fused<<<dim3(NB / 2), dim3(NTH), 0, stream>>>(
            xin, wih[0], whh[0], bih[0], bhh[0],
            wih[1], whh[1], bih[1], bhh[1],
            wih[2], whh[2], bih[2], bhh[2], out);
    }
}

// Round 8
// 796.053 us; speedup vs baseline: 1.1844x; 1.1844x over previous
//
#include <hip/hip_runtime.h>

namespace {

constexpr int NTH = 512;   // threads per block (rec + fallback)
constexpr int NB  = 512;   // GRU batch (original T)
constexpr int HID = 128;
constexpr int G3  = 384;
constexpr int SS  = 128;   // scan steps (original B)
constexpr int CH  = 20;    // padded LDS chunk stride for fallback kernel

typedef float    f32x2 __attribute__((ext_vector_type(2)));
typedef float    f32x4 __attribute__((ext_vector_type(4)));
typedef _Float16 f16;
typedef f16      f16x4 __attribute__((ext_vector_type(4)));
typedef f16      f16x8 __attribute__((ext_vector_type(8)));

__device__ __forceinline__ f32x2 pk_fma(f32x2 a, f32x2 b, f32x2 c) {
#if __has_builtin(__builtin_elementwise_fma)
    return __builtin_elementwise_fma(a, b, c);
#else
    f32x2 r; r.x = fmaf(a.x, b.x, c.x); r.y = fmaf(a.y, b.y, c.y); return r;
#endif
}

template <int CTRL>
__device__ __forceinline__ float add_dpp(float v) {
    int moved = __builtin_amdgcn_update_dpp(0, __float_as_int(v), CTRL, 0xf, 0xf, true);
    return v + __int_as_float(moved);
}
__device__ __forceinline__ float wave_red8(float v) {
    v = add_dpp<0x111>(v);
    v = add_dpp<0x112>(v);
    v = add_dpp<0x114>(v);
    return v;
}

__device__ __forceinline__ float dot4acc(float4 a, float4 b, float acc) {
    acc = fmaf(a.x, b.x, acc);
    acc = fmaf(a.y, b.y, acc);
    acc = fmaf(a.z, b.z, acc);
    acc = fmaf(a.w, b.w, acc);
    return acc;
}

__device__ __forceinline__ float fsig(float x)  { return 1.f / (1.f + __expf(-x)); }
__device__ __forceinline__ float ftanh_(float x){ const float e = __expf(2.f * x); return 1.f - 2.f / (e + 1.f); }

__device__ __forceinline__ f16x8 zero8() {
    f16x8 z;
    #pragma unroll
    for (int e = 0; e < 8; ++e) z[e] = (f16)0.f;
    return z;
}

// ============================================================================
// Kernel 1: px GEMM via MFMA (f16 inputs, fp32 accum).
// px[m][g] = sum_k X[m][k]*W[g][k] + bih[g] + (g<256 ? bhh[g] : 0)
// K = KIN (64 or 128) fits entirely in LDS: no k-loop. 256 thr = 4 waves.
// Wave w computes rows w*32..w*32+31 x all 128 g of this g-block.
// Single-f16 W (err ~5e-4 on px, inside budget). X f16 likewise.
// LDS XOR-swizzled ( ^ (row&7)<<3 in f16 units ) to kill ds_read_b128
// bank conflicts; same scheme as the (harness-verified) rec hlds layout.
// ============================================================================
template <int KIN>
__global__ __launch_bounds__(256, 2) void px_mfma(
    const float* __restrict__ X,    // [65536][KIN]
    const float* __restrict__ Wm,   // [384][KIN]  (w_ih)
    const float* __restrict__ bih,
    const float* __restrict__ bhh,
    float* __restrict__ px)         // [65536][384]
{
    __shared__ _Float16 Xl[128 * 128];  // [m][k], row stride 128, swizzled
    __shared__ _Float16 Wl[128 * 128];  // [g][k], row stride 128, swizzled

    constexpr int KSH = (KIN == 64) ? 6 : 7;
    constexpr int NKT = KIN / 32;

    const int tid = threadIdx.x;
    const int m0  = blockIdx.x * 128;
    const int g0  = blockIdx.y * 128;

    // ---- stage X, W as f16 into swizzled LDS ----
    #pragma unroll
    for (int i = tid * 4; i < 128 * KIN; i += 1024) {
        const int m = i >> KSH, k = i & (KIN - 1);
        const float4 v = *reinterpret_cast<const float4*>(X + (size_t)(m0 + m) * KIN + k);
        f16x4 h; h[0] = (f16)v.x; h[1] = (f16)v.y; h[2] = (f16)v.z; h[3] = (f16)v.w;
        *reinterpret_cast<f16x4*>(&Xl[(m * 128 + k) ^ ((m & 7) << 3)]) = h;
    }
    #pragma unroll
    for (int i = tid * 4; i < 128 * KIN; i += 1024) {
        const int g = i >> KSH, k = i & (KIN - 1);
        const float4 v = *reinterpret_cast<const float4*>(Wm + (size_t)(g0 + g) * KIN + k);
        f16x4 h; h[0] = (f16)v.x; h[1] = (f16)v.y; h[2] = (f16)v.z; h[3] = (f16)v.w;
        *reinterpret_cast<f16x4*>(&Wl[(g * 128 + k) ^ ((g & 7) << 3)]) = h;
    }
    __syncthreads();

    const int lane = tid & 63;
    const int wid  = tid >> 6;      // wave 0..3 -> rows wid*32..+31
    const int l15  = lane & 15;
    const int q    = lane >> 4;

    // A-frags for the wave's 2 m-tiles (lane l: row mt*16+l15, k = kt*32+q*8+e)
    f16x8 Af[2][NKT];
    #pragma unroll
    for (int mt = 0; mt < 2; ++mt)
        #pragma unroll
        for (int kt = 0; kt < NKT; ++kt)
            Af[mt][kt] = *reinterpret_cast<const f16x8*>(
                &Xl[(((wid * 2 + mt) * 16 + l15) * 128 + kt * 32 + q * 8) ^ ((l15 & 7) << 3)]);

    f32x4 acc[2][8];
    #pragma unroll
    for (int mt = 0; mt < 2; ++mt)
        #pragma unroll
        for (int gt = 0; gt < 8; ++gt) acc[mt][gt] = f32x4{0.f, 0.f, 0.f, 0.f};

    #pragma unroll
    for (int gt = 0; gt < 8; ++gt) {
        f16x8 Bf[NKT];
        #pragma unroll
        for (int kt = 0; kt < NKT; ++kt)
            Bf[kt] = *reinterpret_cast<const f16x8*>(
                &Wl[((gt * 16 + l15) * 128 + kt * 32 + q * 8) ^ ((l15 & 7) << 3)]);
        #pragma unroll
        for (int kt = 0; kt < NKT; ++kt) {
            acc[0][gt] = __builtin_amdgcn_mfma_f32_16x16x32_f16(Af[0][kt], Bf[kt], acc[0][gt], 0, 0, 0);
            acc[1][gt] = __builtin_amdgcn_mfma_f32_16x16x32_f16(Af[1][kt], Bf[kt], acc[1][gt], 0, 0, 0);
        }
    }

    // ---- epilogue: bias + store (C row = q*4+r within tile, col = l15) ----
    #pragma unroll
    for (int gt = 0; gt < 8; ++gt) {
        const int g = g0 + gt * 16 + l15;
        float bg = bih[g];
        if (g0 < 256) bg += bhh[g];
        #pragma unroll
        for (int mt = 0; mt < 2; ++mt) {
            #pragma unroll
            for (int r = 0; r < 4; ++r) {
                const int m = m0 + (wid * 2 + mt) * 16 + q * 4 + r;
                px[(size_t)m * G3 + g] = acc[mt][gt][r] + bg;
            }
        }
    }
}

// ============================================================================
// Kernel 2: MFMA recurrence v4. 32 blocks x 512 threads; 16 rows/block.
// Changes vs v3 (223us): coalesced px [m][384] + 1-step register prefetch
// (hides HBM latency); raw s_barrier with lgkmcnt-only drain (y-stores and
// px prefetch stay in flight across the barrier - no vmcnt(0) per step).
// W single f16 resident; h split hi/lo (A-side Markidis), 24 MFMA/step.
// ============================================================================
__global__ __launch_bounds__(NTH, 1) void gru_rec_v4(
    const float* __restrict__ px,   // [SS*NB][384]  (biases folded: bih all, bhh for r,z)
    const float* __restrict__ whh,  // [384][128]
    const float* __restrict__ bhh,  // [384]
    float* __restrict__ yd)         // [SS][NB][HID]
{
    __shared__ _Float16 hlds[2][2][16 * HID];   // [dbuf][hi|lo][m*128+k], XOR-swizzled

    const int tid  = threadIdx.x;
    const int lane = tid & 63;
    const int w    = tid >> 6;      // wave 0..7 = gate-column tile
    const int l15  = lane & 15;
    const int q    = lane >> 4;     // lane quadrant 0..3
    const int colc = w * 16 + l15;  // hidden column owned (0..127)
    const int row0 = blockIdx.x * 16;

    // ---- W fragments, single f16 (B-frag: lane l holds W[kt*32+q*8+e][colc]) ----
    f16x8 Wf[3][4];
    #pragma unroll
    for (int g = 0; g < 3; ++g) {
        #pragma unroll
        for (int kt = 0; kt < 4; ++kt) {
            const float* src = whh + (size_t)(g * HID + colc) * HID + kt * 32 + q * 8;
            const float4 a = *reinterpret_cast<const float4*>(src);
            const float4 b = *reinterpret_cast<const float4*>(src + 4);
            f16x8 f;
            f[0] = (f16)a.x; f[1] = (f16)a.y; f[2] = (f16)a.z; f[3] = (f16)a.w;
            f[4] = (f16)b.x; f[5] = (f16)b.y; f[6] = (f16)b.z; f[7] = (f16)b.w;
            Wf[g][kt] = f;
        }
    }
    const float bhn = bhh[256 + colc];

    float hstate[4] = {0.f, 0.f, 0.f, 0.f};
    f16x8 Ahi[4], Alo[4];
    #pragma unroll
    for (int kt = 0; kt < 4; ++kt) { Ahi[kt] = zero8(); Alo[kt] = zero8(); }

    // px base: rows row0+4q+r, cols {colc, 128+colc, 256+colc}; coalesced over l15
    const float* pxbase = px + (size_t)(row0 + q * 4) * G3 + colc;
    float* ybase = yd + (size_t)(row0 + q * 4) * HID + colc;

    // prologue: px for step 0
    float pcr[4], pcz[4], pcn[4];
    #pragma unroll
    for (int r = 0; r < 4; ++r) {
        pcr[r] = pxbase[(size_t)r * G3];
        pcz[r] = pxbase[(size_t)r * G3 + 128];
        pcn[r] = pxbase[(size_t)r * G3 + 256];
    }

    #pragma unroll 1
    for (int s = 0; s < SS; ++s) {
        // ---- prefetch px for s+1 (consumed next iter: latency fully hidden) ----
        const int sp = (s + 1 < SS) ? s + 1 : s;
        const float* pb = pxbase + (size_t)sp * NB * G3;
        float nr[4], nz[4], nn2[4];
        #pragma unroll
        for (int r = 0; r < 4; ++r) {
            nr[r]  = pb[(size_t)r * G3];
            nz[r]  = pb[(size_t)r * G3 + 128];
            nn2[r] = pb[(size_t)r * G3 + 256];
        }

        // ---- gh = h @ w_hh.T : 24 MFMA, 6 independent chains of depth 4 ----
        f32x4 a0R = {0.f,0.f,0.f,0.f}, a1R = {0.f,0.f,0.f,0.f};
        f32x4 a0Z = {0.f,0.f,0.f,0.f}, a1Z = {0.f,0.f,0.f,0.f};
        f32x4 a0N = {0.f,0.f,0.f,0.f}, a1N = {0.f,0.f,0.f,0.f};
        #pragma unroll
        for (int kt = 0; kt < 2; ++kt) {
            a0R = __builtin_amdgcn_mfma_f32_16x16x32_f16(Ahi[kt],     Wf[0][kt],     a0R, 0, 0, 0);
            a0Z = __builtin_amdgcn_mfma_f32_16x16x32_f16(Ahi[kt],     Wf[1][kt],     a0Z, 0, 0, 0);
            a0N = __builtin_amdgcn_mfma_f32_16x16x32_f16(Ahi[kt],     Wf[2][kt],     a0N, 0, 0, 0);
            a1R = __builtin_amdgcn_mfma_f32_16x16x32_f16(Ahi[kt + 2], Wf[0][kt + 2], a1R, 0, 0, 0);
            a1Z = __builtin_amdgcn_mfma_f32_16x16x32_f16(Ahi[kt + 2], Wf[1][kt + 2], a1Z, 0, 0, 0);
            a1N = __builtin_amdgcn_mfma_f32_16x16x32_f16(Ahi[kt + 2], Wf[2][kt + 2], a1N, 0, 0, 0);
        }
        #pragma unroll
        for (int kt = 0; kt < 2; ++kt) {
            a0R = __builtin_amdgcn_mfma_f32_16x16x32_f16(Alo[kt],     Wf[0][kt],     a0R, 0, 0, 0);
            a0Z = __builtin_amdgcn_mfma_f32_16x16x32_f16(Alo[kt],     Wf[1][kt],     a0Z, 0, 0, 0);
            a0N = __builtin_amdgcn_mfma_f32_16x16x32_f16(Alo[kt],     Wf[2][kt],     a0N, 0, 0, 0);
            a1R = __builtin_amdgcn_mfma_f32_16x16x32_f16(Alo[kt + 2], Wf[0][kt + 2], a1R, 0, 0, 0);
            a1Z = __builtin_amdgcn_mfma_f32_16x16x32_f16(Alo[kt + 2], Wf[1][kt + 2], a1Z, 0, 0, 0);
            a1N = __builtin_amdgcn_mfma_f32_16x16x32_f16(Alo[kt + 2], Wf[2][kt + 2], a1N, 0, 0, 0);
        }
        const f32x4 accR = a0R + a1R;
        const f32x4 accZ = a0Z + a1Z;
        const f32x4 accN = a0N + a1N;

        // ---- gates (C row m=q*4+r, col=colc), y store, h->LDS f16 hi/lo ----
        _Float16* wb0 = &hlds[(s + 1) & 1][0][0];
        _Float16* wb1 = &hlds[(s + 1) & 1][1][0];
        #pragma unroll
        for (int r = 0; r < 4; ++r) {
            const float rr = fsig(pcr[r] + accR[r]);
            const float zz = fsig(pcz[r] + accZ[r]);
            const float nnv = ftanh_(pcn[r] + rr * (accN[r] + bhn));
            const float hn = (1.f - zz) * nnv + zz * hstate[r];
            hstate[r] = hn;
            ybase[((size_t)s * NB + (size_t)r) * HID] = hn;
            const int m   = q * 4 + r;
            const int idx = (m * HID + colc) ^ ((m & 7) << 3);
            const f16 hh = (f16)hn;
            wb0[idx] = hh;
            wb1[idx] = (f16)(hn - (float)hh);
        }

        // rotate px prefetch into current
        #pragma unroll
        for (int r = 0; r < 4; ++r) { pcr[r] = nr[r]; pcz[r] = nz[r]; pcn[r] = nn2[r]; }

        // ---- raw barrier: drain LDS only (y-stores / px loads stay in flight) ----
        asm volatile("s_waitcnt lgkmcnt(0)" ::: "memory");
        __builtin_amdgcn_sched_barrier(0);
        __builtin_amdgcn_s_barrier();
        __builtin_amdgcn_sched_barrier(0);
        asm volatile("" ::: "memory");

        // ---- A-frags for h[s+1]: lane l reads h[l15][kt*32+q*8 .. +7] ----
        const _Float16* rb0 = &hlds[(s + 1) & 1][0][0];
        const _Float16* rb1 = &hlds[(s + 1) & 1][1][0];
        #pragma unroll
        for (int kt = 0; kt < 4; ++kt) {
            const int idx = (l15 * HID + kt * 32 + q * 8) ^ ((l15 & 7) << 3);
            Ahi[kt] = *reinterpret_cast<const f16x8*>(rb0 + idx);
            Alo[kt] = *reinterpret_cast<const f16x8*>(rb1 + idx);
        }
    }
}

// ============================================================================
// Fallback: R1 fused kernel (used only if workspace is too small for px).
// ============================================================================
__global__ __launch_bounds__(NTH) void gru3_fused(
    const float* __restrict__ xin,
    const float* __restrict__ wih0, const float* __restrict__ whh0,
    const float* __restrict__ bih0, const float* __restrict__ bhh0,
    const float* __restrict__ wih1, const float* __restrict__ whh1,
    const float* __restrict__ bih1, const float* __restrict__ bhh1,
    const float* __restrict__ wih2, const float* __restrict__ whh2,
    const float* __restrict__ bih2, const float* __restrict__ bhh2,
    float* __restrict__ out)
{
    __shared__ __align__(16) float xb[2][2 * 8 * CH];
    __shared__ __align__(16) float hb[2 * 8 * CH];
    __shared__ float pxl[2][G3];
    __shared__ float ghl[2][G3];
    __shared__ float bsum[2 * HID];
    __shared__ float bin_[HID];
    __shared__ float bhn_[HID];

    const int tid  = threadIdx.x;
    const int kgrp = tid & 7;
    const int gt   = tid >> 3;
    const int g0   = gt * 6;
    const int row0 = blockIdx.x * 2;

    float4 wih[6][4];
    float4 whh[6][4];

    for (int layer = 0; layer < 3; ++layer) {
        const float *wi, *wh, *bi, *bh, *xs;
        float* yd;
        int kin;
        if (layer == 0)      { wi = wih0; wh = whh0; bi = bih0; bh = bhh0; xs = xin; yd = out; kin = 64;  }
        else if (layer == 1) { wi = wih1; wh = whh1; bi = bih1; bh = bhh1; xs = out; yd = out; kin = HID; }
        else                 { wi = wih2; wh = whh2; bi = bih2; bh = bhh2; xs = out; yd = out; kin = HID; }

        #pragma unroll
        for (int gg = 0; gg < 6; ++gg) {
            const int g = g0 + gg;
            #pragma unroll
            for (int qq = 0; qq < 4; ++qq) {
                const int k = kgrp * 16 + qq * 4;
                whh[gg][qq] = *reinterpret_cast<const float4*>(wh + g * HID + k);
                if (k < kin)
                    wih[gg][qq] = *reinterpret_cast<const float4*>(wi + g * kin + k);
                else
                    wih[gg][qq] = make_float4(0.f, 0.f, 0.f, 0.f);
            }
        }

        for (int i = tid; i < 2 * HID; i += NTH) bsum[i] = bi[i] + bh[i];
        for (int i = tid; i < HID; i += NTH) { bin_[i] = bi[256 + i]; bhn_[i] = bh[256 + i]; }
        for (int i = tid; i < 2 * 8 * CH; i += NTH) { hb[i] = 0.f; xb[0][i] = 0.f; xb[1][i] = 0.f; }
        __syncthreads();
        if (tid < 256) {
            const int n = tid >> 7, j = tid & 127;
            if (j < kin)
                xb[0][n * (8 * CH) + (j >> 4) * CH + (j & 15)] = xs[(0 * NB + row0 + n) * kin + j];
        }
        __syncthreads();

        float ypend = 0.f;
        bool  have_y = false;

        for (int s = 0; s < SS; ++s) {
            float xpref = 0.f;
            if (tid >= 256) {
                const int t2 = tid - 256;
                const int n = t2 >> 7, j = t2 & 127;
                if (s + 1 < SS && j < kin)
                    xpref = xs[((s + 1) * NB + row0 + n) * kin + j];
            } else if (have_y) {
                const int n = tid >> 7, j = tid & 127;
                yd[((s - 1) * NB + row0 + n) * HID + j] = ypend;
            }

            float accp[2][6], accg[2][6];
            #pragma unroll
            for (int n = 0; n < 2; ++n)
                #pragma unroll
                for (int gg = 0; gg < 6; ++gg) { accp[n][gg] = 0.f; accg[n][gg] = 0.f; }

            const float* xcur = xb[s & 1];
            #pragma unroll
            for (int qq = 0; qq < 4; ++qq) {
                const int off = kgrp * CH + qq * 4;
                const float4 x0 = *reinterpret_cast<const float4*>(xcur + off);
                const float4 x1 = *reinterpret_cast<const float4*>(xcur + 8 * CH + off);
                const float4 h0 = *reinterpret_cast<const float4*>(hb + off);
                const float4 h1 = *reinterpret_cast<const float4*>(hb + 8 * CH + off);
                #pragma unroll
                for (int gg = 0; gg < 6; ++gg) {
                    accp[0][gg] = dot4acc(x0, wih[gg][qq], accp[0][gg]);
                    accp[1][gg] = dot4acc(x1, wih[gg][qq], accp[1][gg]);
                    accg[0][gg] = dot4acc(h0, whh[gg][qq], accg[0][gg]);
                    accg[1][gg] = dot4acc(h1, whh[gg][qq], accg[1][gg]);
                }
            }

            #pragma unroll
            for (int n = 0; n < 2; ++n)
                #pragma unroll
                for (int gg = 0; gg < 6; ++gg) {
                    const float rp = wave_red8(accp[n][gg]);
                    const float rg = wave_red8(accg[n][gg]);
                    if (kgrp == 7) { pxl[n][g0 + gg] = rp; ghl[n][g0 + gg] = rg; }
                }
            __syncthreads();

            if (tid < 256) {
                const int n = tid >> 7, j = tid & 127;
                const float pr = pxl[n][j]       + ghl[n][j]       + bsum[j];
                const float pz = pxl[n][j + 128] + ghl[n][j + 128] + bsum[j + 128];
                const float gn = ghl[n][j + 256] + bhn_[j];
                const float pn = pxl[n][j + 256] + bin_[j];
                const float r  = fsig(pr);
                const float z  = fsig(pz);
                const float nnv = ftanh_(pn + r * gn);
                const int hoff = n * (8 * CH) + (j >> 4) * CH + (j & 15);
                const float hold = hb[hoff];
                const float hnew = (1.f - z) * nnv + z * hold;
                hb[hoff] = hnew;
                ypend = hnew;
                have_y = true;
            } else {
                const int t2 = tid - 256;
                const int n = t2 >> 7, j = t2 & 127;
                if (s + 1 < SS && j < kin)
                    xb[(s + 1) & 1][n * (8 * CH) + (j >> 4) * CH + (j & 15)] = xpref;
            }
            __syncthreads();
        }

        if (tid < 256) {
            const int n = tid >> 7, j = tid & 127;
            yd[((SS - 1) * NB + row0 + n) * HID + j] = ypend;
        }
        __syncthreads();
    }
}

}  // namespace

extern "C" void kernel_launch(void* const* d_in, const int* in_sizes, int n_in,
                              void* d_out, int out_size, void* d_ws, size_t ws_size,
                              hipStream_t stream)
{
    (void)in_sizes; (void)n_in; (void)out_size;
    const float* xin = (const float*)d_in[0];
    const float* wih[3] = { (const float*)d_in[1], (const float*)d_in[5], (const float*)d_in[9]  };
    const float* whh[3] = { (const float*)d_in[2], (const float*)d_in[6], (const float*)d_in[10] };
    const float* bih[3] = { (const float*)d_in[3], (const float*)d_in[7], (const float*)d_in[11] };
    const float* bhh[3] = { (const float*)d_in[4], (const float*)d_in[8], (const float*)d_in[12] };
    float* out = (float*)d_out;

    const size_t need = (size_t)SS * NB * G3 * sizeof(float);  // 96 MB px buffer
    if (ws_size >= need) {
        float* px = (float*)d_ws;
        for (int l = 0; l < 3; ++l) {
            const float* A = (l == 0) ? xin : out;
            if (l == 0)
                px_mfma<64><<<dim3((SS * NB) / 128, 3), dim3(256), 0, stream>>>(
                    A, wih[l], bih[l], bhh[l], px);
            else
                px_mfma<128><<<dim3((SS * NB) / 128, 3), dim3(256), 0, stream>>>(
                    A, wih[l], bih[l], bhh[l], px);
            gru_rec_v4<<<dim3(NB / 16), dim3(NTH), 0, stream>>>(px, whh[l], bhh[l], out);
        }
    } else {
        gru3_fused<<<dim3(NB / 2), dim3(NTH), 0, stream>>>(
            xin, wih[0], whh[0], bih[0], bhh[0],
            wih[1], whh[1], bih[1], bhh[1],
            wih[2], whh[2], bih[2], bhh[2], out);
    }
}